// Round 8
// baseline (372.595 us; speedup 1.0000x reference)
//
#include <hip/hip_runtime.h>
#include <stdint.h>

#define BSZ 16
#define TT  2048
#define NSEM 2048
#define DIM 128
#define ORS 1024          // shorts per output row (512 floats)
#define LOG2E 1.4426950408889634f
#define LN2   0.6931471805599453f

typedef __attribute__((ext_vector_type(8))) short short8;
typedef __attribute__((ext_vector_type(4))) float floatx4;

__device__ __forceinline__ unsigned short f2bf(float f){       // RNE
  unsigned u = __float_as_uint(f);
  return (unsigned short)((u + 0x7fffu + ((u >> 16) & 1u)) >> 16);
}
__device__ __forceinline__ unsigned pkbf(float a, float b){    // 2xf32 -> packed bf16 (RNE, HW)
  unsigned r;
  asm("v_cvt_pk_bf16_f32 %0, %1, %2" : "=v"(r) : "v"(a), "v"(b));
  return r;
}
__device__ __forceinline__ float e2(float x){                  // 2^x, single v_exp
#if __has_builtin(__builtin_amdgcn_exp2f)
  return __builtin_amdgcn_exp2f(x);
#else
  return exp2f(x);
#endif
}
__device__ __forceinline__ void ld8f(const float* p, float* v){
  floatx4 a = *(const floatx4*)p;
  floatx4 b = *(const floatx4*)(p + 4);
  v[0]=a[0]; v[1]=a[1]; v[2]=a[2]; v[3]=a[3];
  v[4]=b[0]; v[5]=b[1]; v[6]=b[2]; v[7]=b[3];
}
// async global->LDS: 64 lanes x 16B; LDS dest is wave-uniform base + lane*16.
__device__ __forceinline__ void gload_lds16(const unsigned short* g, unsigned short* l){
  __builtin_amdgcn_global_load_lds((const __attribute__((address_space(1))) void*)g,
                                   (__attribute__((address_space(3))) void*)l, 16, 0, 0);
}

// Staging layout (in out buffer, shorts [512,1024) of rows b*TT + c, 1KB each):
//   KST chunk cK = nblk*4 + kc            (cK in [0,512))   : [quad][l15][8] = K[nblk*16+l15][kc*32+quad*8+j]
//   VST chunk cV = 512 + ntile*16 + kt*8 + dc (cV in [512,1024)) : [quad][l15][8] = V[ntile*64+kt*32+quad*8+j][dc*16+l15]
// One chunk == one coalesced 1KB wave access (16B/lane).

// ---------------- kernel 1: prep ----------------
// grid 512 (b = bx>>5, n0 = (bx&31)*64), 256 thr. colB pre-scaled by LOG2E (exp2 domain).
__global__ __launch_bounds__(256) void prep_kernel(const float* __restrict__ sem,
                                                   const float* __restrict__ W,
                                                   float* __restrict__ colB,
                                                   unsigned short* __restrict__ outw){
  __shared__ unsigned short tile[DIM * 72];        // [d][n] bf16, stride 72 (144B, 16B-mult)
  const int tid = threadIdx.x;
  const int b  = blockIdx.x >> 5;
  const int n0 = (blockIdx.x & 31) * 64;

  // phase 1: row r (64 rows), col chunk c (32 cols)
  const int r = tid >> 2, cc = tid & 3, c = cc * 32;
  const float* src = sem + ((size_t)(b * NSEM + n0 + r)) * DIM + c;
  float v[32];
  ld8f(src, v); ld8f(src + 8, v + 8); ld8f(src + 16, v + 16); ld8f(src + 24, v + 24);
  alignas(16) unsigned short bf[32];
  float cpart = 0.f;
  #pragma unroll
  for (int j = 0; j < 32; ++j){
    bf[j] = f2bf(v[j]);
    cpart += v[j] * W[DIM + c + j];                // w2 dot partial
  }
  // KST write: chunk (nblk, kc=cc), row l15 = r&15. 4 x 16B at stride 256B.
  {
    const int nblk = (n0 >> 4) + (r >> 4);
    const int l15r = r & 15;
    unsigned short* base = outw + ((size_t)(b * TT + nblk * 4 + cc)) * ORS + 512;
    const uint4* s4 = (const uint4*)bf;
    #pragma unroll
    for (int q = 0; q < 4; ++q)
      *(uint4*)(base + q * 128 + l15r * 8) = s4[q];
  }
  // LDS transpose stage
  #pragma unroll
  for (int j = 0; j < 32; ++j) tile[(c + j) * 72 + r] = bf[j];
  // colB reduce over the 4 col-chunks (lanes differing in bits 0..1)
  cpart += __shfl_xor(cpart, 1);
  cpart += __shfl_xor(cpart, 2);
  if (cc == 0) colB[b * NSEM + n0 + r] = cpart * LOG2E;   // exp2 domain
  __syncthreads();

  // phase 2: VST write. kt = tid>>7 (2), dc = (tid>>4)&7 (8), l15 = tid&15.
  {
    const int kt = tid >> 7, dc = (tid >> 4) & 7, l15 = tid & 15;
    const int d = dc * 16 + l15;
    const int ntile = n0 >> 6;
    unsigned short* base = outw + ((size_t)(b * TT + 512 + ntile * 16 + kt * 8 + dc)) * ORS + 512;
    #pragma unroll
    for (int q = 0; q < 4; ++q){
      uint4 tv = *(const uint4*)&tile[d * 72 + kt * 32 + q * 8];
      *(uint4*)(base + q * 128 + l15 * 8) = tv;
    }
  }
}

// ---------------- kernel 2: flash attention, 8-wave blocks, n-split x2 ----------------
// grid 512 (b = bx>>5, 64-row t-block), 512 thr = 8 waves: tg = wv&3 (t-group of 16),
// h = wv>>2 (n-half: n in [h*1024, h*1024+1024), 16 iters of 64 n).
// K: LDS double-buffered per half (16KB tiles), shared by the 4 waves of that half.
// V: direct from global (coalesced VST chunks, L2/L3-resident).
// Swapped QK (mfma(K,Q)) -> row-local softmax in exp2 domain; cvt_pk P conversion;
// XOR-swizzled pbuf; defer-max. End: pairwise half-merge via LDS aliased over kvt.
// 4 waves/SIMD (16/CU): TLP finally covers the DS/latency gaps.
__global__ __launch_bounds__(512, 4) void flash_kernel(const float* __restrict__ aud,
                                                    const float* __restrict__ W,
                                                    const float* __restrict__ colB,
                                                    float* __restrict__ m_ws,
                                                    float* __restrict__ outf,
                                                    const unsigned short* __restrict__ outw){
  __shared__ alignas(16) unsigned short kvt[2][2][16][512];   // 2 halves x 2 bufs x 16KB = 64 KB
  __shared__ alignas(16) unsigned short pbuf[8][1024];        // per-wave P, [16 rows][64], 16 KB

  const int tid  = threadIdx.x;
  const int wv   = tid >> 6;
  const int lane = tid & 63;
  const int quad = lane >> 4;
  const int l15  = lane & 15;
  const int h    = wv >> 2;                                   // n-half
  const int tg   = wv & 3;                                    // t-group
  const int b    = blockIdx.x >> 5;
  const int t0w  = (blockIdx.x & 31) * 64 + tg * 16;          // this wave's 16 rows

  // per-lane global staging base (shorts [512,1024) of rows b*TT + c)
  const unsigned short* stage = outw + (size_t)b * TT * ORS + 512 + lane * 8;

  // prologue: stage K tile 0 of this half (4 chunks per wave; half-tile = 16 chunks)
  #pragma unroll
  for (int jj = 0; jj < 4; ++jj)
    gload_lds16(stage + (size_t)(h * 256 + tg * 4 + jj) * ORS, &kvt[h][0][tg * 4 + jj][0]);

  // q A-frags (aud*w3*log2e -> bf16, exp2 domain) + rowA partial (fp32 dot aud,w1)
  const float* audRow = aud + ((size_t)b * TT + t0w + l15) * DIM;
  short8 qf[4];
  float rowA_part = 0.f;
  #pragma unroll
  for (int kc = 0; kc < 4; ++kc){
    int d0 = kc * 32 + quad * 8;
    float av[8], w3v[8], w1v[8];
    ld8f(audRow + d0, av);
    ld8f(W + 2 * DIM + d0, w3v);
    ld8f(W + d0, w1v);
    alignas(16) unsigned short tmp[8];
    #pragma unroll
    for (int j = 0; j < 8; ++j){
      tmp[j] = f2bf(av[j] * (w3v[j] * LOG2E));
      rowA_part += av[j] * w1v[j];
    }
    qf[kc] = *(const short8*)tmp;
  }
  rowA_part += __shfl_xor(rowA_part, 16);
  rowA_part += __shfl_xor(rowA_part, 32);   // full-d dot for row t0w + l15, replicated

  float m_run = -1e30f, l_run = 0.f;        // per-lane: row t = t0w + l15 (exp2 domain)
  float m_true = -1e30f;                    // exact running max (exp2 domain)
  floatx4 o[8];
  #pragma unroll
  for (int dc = 0; dc < 8; ++dc){
    #pragma unroll
    for (int r = 0; r < 4; ++r) o[dc][r] = 0.f;
  }

  const float* colBb = colB + b * NSEM;
  unsigned short* pb = &pbuf[wv][0];
  const int swz = (l15 & 7);                // pbuf XOR key (per row)

  __syncthreads();                                  // K tile 0 staged

  for (int it = 0; it < 16; ++it){
    const int n0 = h * 1024 + it * 64;

    // colB addends first (their waitcnt then doesn't drain later VMEM)
    floatx4 cbv[4];
    #pragma unroll
    for (int s = 0; s < 4; ++s) cbv[s] = *(const floatx4*)(colBb + n0 + s*16 + quad*4);

    // prefetch K tile it+1 (DMA, no regs)
    if (it + 1 < 16){
      #pragma unroll
      for (int jj = 0; jj < 4; ++jj)
        gload_lds16(stage + (size_t)(h * 256 + (it + 1) * 16 + tg * 4 + jj) * ORS,
                    &kvt[h][(it + 1) & 1][tg * 4 + jj][0]);
    }

    // V frags: direct global loads (consumed at PV; full-iteration latency window)
    const int cV = 512 + (h * 16 + it) * 16;
    short8 vf[16];
    #pragma unroll
    for (int i = 0; i < 16; ++i) vf[i] = *(const short8*)(stage + (size_t)(cV + i) * ORS);
    __builtin_amdgcn_sched_barrier(0);      // pin: all VMEM issued before compute

    const unsigned short* kvb = &kvt[h][it & 1][0][0] + lane * 8;

    // ---- QK swapped: sacc[s] = K_frag x Q -> S[n=quad*4+r][t=l15] (exp2 domain) ----
    floatx4 sacc[4];
    #pragma unroll
    for (int s = 0; s < 4; ++s){ sacc[s][0]=0.f; sacc[s][1]=0.f; sacc[s][2]=0.f; sacc[s][3]=0.f; }
    #pragma unroll
    for (int s = 0; s < 4; ++s){
      #pragma unroll
      for (int kc = 0; kc < 4; ++kc){
        short8 kf = *(const short8*)(kvb + (s*4 + kc) * 512);
        sacc[s] = __builtin_amdgcn_mfma_f32_16x16x32_bf16(kf, qf[kc], sacc[s], 0, 0, 0);
      }
    }

    // ---- online softmax, row-local (t = l15), defer-max THR=8 (log2 units) ----
    float v[4][4];
    #pragma unroll
    for (int s = 0; s < 4; ++s){
      #pragma unroll
      for (int r = 0; r < 4; ++r) v[s][r] = sacc[s][r] + cbv[s][r];
    }
    float mq[4];
    #pragma unroll
    for (int s = 0; s < 4; ++s)
      mq[s] = fmaxf(fmaxf(v[s][0], v[s][1]), fmaxf(v[s][2], v[s][3]));
    float mx = fmaxf(fmaxf(mq[0], mq[1]), fmaxf(mq[2], mq[3]));
    mx = fmaxf(mx, __shfl_xor(mx, 16));
    mx = fmaxf(mx, __shfl_xor(mx, 32));
    m_true = fmaxf(m_true, mx);

    const bool defer = (__all(mx - m_run <= 8.0f) != 0);   // wave-uniform
    float al = 1.0f;
    if (!defer){
      float mnew = fmaxf(m_run, mx);
      al = e2(m_run - mnew);
      m_run = mnew;
    }
    float e[4][4];
    #pragma unroll
    for (int s = 0; s < 4; ++s){
      #pragma unroll
      for (int r = 0; r < 4; ++r) e[s][r] = e2(v[s][r] - m_run);
    }
    float sq[4];
    #pragma unroll
    for (int s = 0; s < 4; ++s)
      sq[s] = (e[s][0] + e[s][1]) + (e[s][2] + e[s][3]);
    float ps = (sq[0] + sq[1]) + (sq[2] + sq[3]);
    ps += __shfl_xor(ps, 16);
    ps += __shfl_xor(ps, 32);
    l_run = l_run * al + ps;

    // P staging: row t=l15; hw cvt_pk pairs -> ds_write_b64 at XOR-swizzled chunk
    #pragma unroll
    for (int s = 0; s < 4; ++s){
      unsigned u0 = pkbf(e[s][0], e[s][1]);
      unsigned u1 = pkbf(e[s][2], e[s][3]);
      const int chk = 2*s + (quad >> 1);                     // 16B chunk within row
      unsigned short* pr = pb + l15 * 64 + ((chk ^ swz) << 3) + (quad & 1) * 4;
      *(uint64_t*)pr = (uint64_t)u0 | ((uint64_t)u1 << 32);
    }

    // o-rescale only when max actually moved (rare after warm-up)
    if (!defer){
      float aB[4];
      #pragma unroll
      for (int r = 0; r < 4; ++r) aB[r] = __shfl(al, quad*4 + r);
      #pragma unroll
      for (int dc = 0; dc < 8; ++dc){
        #pragma unroll
        for (int r = 0; r < 4; ++r) o[dc][r] *= aB[r];
      }
    }

    // wave-local LDS visibility (in-order DS per wave; just drain writes)
    asm volatile("s_waitcnt lgkmcnt(0)" ::: "memory");
    short8 pf0 = *(const short8*)(pb + l15 * 64 + ((quad       ^ swz) << 3));
    short8 pf1 = *(const short8*)(pb + l15 * 64 + (((4 | quad) ^ swz) << 3));

    // ---- PV: O += P . sem, V frags in regs ----
    #pragma unroll
    for (int kt = 0; kt < 2; ++kt){
      short8 pf = kt ? pf1 : pf0;
      #pragma unroll
      for (int dc = 0; dc < 8; ++dc)
        o[dc] = __builtin_amdgcn_mfma_f32_16x16x32_bf16(pf, vf[kt*8 + dc], o[dc], 0, 0, 0);
    }

    // tile boundary: K-buffer swap safety + DMA drain (vmcnt0 at barrier)
    __syncthreads();
  }

  // ---- half-merge: h1 publishes (O, m, l, m_true) into LDS aliased over kvt ----
  float* Ob  = (float*)(&kvt[0][0][0][0]);          // [4tg][16][128] fp32 = 32 KB
  float* mlp = Ob + 4 * 16 * 128;                   // [4tg][3][16]
  if (h == 1){
    #pragma unroll
    for (int dc = 0; dc < 8; ++dc){
      #pragma unroll
      for (int r = 0; r < 4; ++r)
        Ob[(tg * 16 + quad * 4 + r) * 128 + dc * 16 + l15] = o[dc][r];
    }
    if (quad == 0){
      mlp[tg * 48 +      l15] = m_run;
      mlp[tg * 48 + 16 + l15] = l_run;
      mlp[tg * 48 + 32 + l15] = m_true;
    }
  }
  __syncthreads();
  if (h == 0){
    float mp  = mlp[tg * 48 +      l15];
    float lp  = mlp[tg * 48 + 16 + l15];
    float mtp = mlp[tg * 48 + 32 + l15];
    float M  = fmaxf(m_run, mp);
    float sA = e2(m_run - M);
    float sB = e2(mp - M);
    float lm = l_run * sA + lp * sB;
    float mt = fmaxf(m_true, mtp);
    float rl = 1.0f / lm;
    float fa = sA * rl, fb = sB * rl;
    float fA[4], fB[4];
    #pragma unroll
    for (int r = 0; r < 4; ++r){ fA[r] = __shfl(fa, quad*4 + r); fB[r] = __shfl(fb, quad*4 + r); }
    float* outB = outf + ((size_t)b * TT + t0w) * 512 + 128;
    #pragma unroll
    for (int dc = 0; dc < 8; ++dc){
      #pragma unroll
      for (int r = 0; r < 4; ++r){
        float op = Ob[(tg * 16 + quad * 4 + r) * 128 + dc * 16 + l15];
        outB[(size_t)(quad*4 + r) * 512 + dc*16 + l15] = o[dc][r] * fA[r] + op * fB[r];
      }
    }
    if (quad == 0)
      m_ws[(size_t)b * TT + t0w + l15] = mt * LN2 + rowA_part;   // back to natural domain
  }
}

// ---------------- kernel 3a: per-chunk max of m ----------------
__global__ __launch_bounds__(256) void bw1_kernel(const float* __restrict__ m_ws,
                                                  float* __restrict__ pmax){
  __shared__ float sA[4];
  const int b = blockIdx.x >> 3, ch = blockIdx.x & 7, tid = threadIdx.x;
  float v = m_ws[(size_t)b * TT + ch * 256 + tid];
  #pragma unroll
  for (int off = 1; off < 64; off <<= 1) v = fmaxf(v, __shfl_xor(v, off));
  if ((tid & 63) == 0) sA[tid >> 6] = v;
  __syncthreads();
  if (tid == 0)
    pmax[blockIdx.x] = fmaxf(fmaxf(sA[0], sA[1]), fmaxf(sA[2], sA[3]));
}

// ---------------- kernel 3b: partial exp-sum + partial a2 ----------------
__global__ __launch_bounds__(256) void bw2_kernel(const float* __restrict__ aud,
                                                  const float* __restrict__ m_ws,
                                                  const float* __restrict__ pmax,
                                                  float* __restrict__ gpart,
                                                  float* __restrict__ part){
  __shared__ float wbuf[256];
  __shared__ float red[16 * 128];
  __shared__ float gs4[4];
  const int b = blockIdx.x >> 3, ch = blockIdx.x & 7, tid = threadIdx.x;

  float gmax = pmax[b * 8];
  #pragma unroll
  for (int i = 1; i < 8; ++i) gmax = fmaxf(gmax, pmax[b * 8 + i]);

  float w = __expf(m_ws[(size_t)b * TT + ch * 256 + tid] - gmax);
  wbuf[tid] = w;
  float sm = w;
  #pragma unroll
  for (int off = 1; off < 64; off <<= 1) sm += __shfl_xor(sm, off);
  if ((tid & 63) == 0) gs4[tid >> 6] = sm;
  __syncthreads();
  if (tid == 0) gpart[blockIdx.x] = (gs4[0] + gs4[1]) + (gs4[2] + gs4[3]);

  const int dg = tid & 15, q = tid >> 4;
  float acc[8] = {0,0,0,0,0,0,0,0};
  const float* ab = aud + ((size_t)b * TT + ch * 256 + q * 16) * DIM + dg * 8;
  for (int i = 0; i < 16; ++i){
    float av[8];
    ld8f(ab + (size_t)i * DIM, av);
    float wt = wbuf[q * 16 + i];
    #pragma unroll
    for (int j = 0; j < 8; ++j) acc[j] += wt * av[j];
  }
  #pragma unroll
  for (int j = 0; j < 8; ++j) red[q * 128 + dg * 8 + j] = acc[j];
  __syncthreads();
  if (tid < 128){
    float s = 0.f;
    #pragma unroll
    for (int q2 = 0; q2 < 16; ++q2) s += red[q2 * 128 + tid];
    part[(size_t)blockIdx.x * 128 + tid] = s;
  }
}

// ---------------- kernel 4: read seg1 (h) + bw partials, write seg0/2/3 ----------------
// bw3 fused: per block (fixed b) reduce part/gpart -> a2[128] in LDS once.
__global__ __launch_bounds__(256) void epi_kernel(const float* __restrict__ aud,
                                                  const float* __restrict__ gpart,
                                                  const float* __restrict__ part,
                                                  float* __restrict__ out){
  __shared__ float a2s[DIM];
  int id = blockIdx.x * 256 + threadIdx.x;        // BSZ*TT*16
  int c = id & 15;
  int t = (id >> 4) & (TT - 1);
  int b = id >> 15;
  size_t row = (size_t)b * TT + t;

  if (threadIdx.x < 128){
    const int d = threadIdx.x;
    float s = 0.f, g = 0.f;
    #pragma unroll
    for (int ch = 0; ch < 8; ++ch){
      s += part[(size_t)(b * 8 + ch) * 128 + d];
      g += gpart[b * 8 + ch];
    }
    a2s[d] = s / g;
  }
  __syncthreads();

  float av[8], gv[8], hv[8];
  ld8f(aud + row * DIM + c * 8, av);
  ld8f(out + row * 512 + 128 + c * 8, hv);        // h (seg1)
  #pragma unroll
  for (int j = 0; j < 8; ++j) gv[j] = a2s[c * 8 + j];

  floatx4 o0a, o0b, o2a, o2b, o3a, o3b;
  #pragma unroll
  for (int j = 0; j < 4; ++j){
    o0a[j] = av[j];           o0b[j] = av[4+j];
    o2a[j] = av[j]*hv[j];     o2b[j] = av[4+j]*hv[4+j];
    o3a[j] = av[j]*gv[j];     o3b[j] = av[4+j]*gv[4+j];
  }
  float* ob = out + row * 512 + c * 8;
  *(floatx4*)(ob)       = o0a;  *(floatx4*)(ob + 4)   = o0b;   // seg0: aud
  *(floatx4*)(ob + 256) = o2a;  *(floatx4*)(ob + 260) = o2b;   // seg2: aud*h
  *(floatx4*)(ob + 384) = o3a;  *(floatx4*)(ob + 388) = o3b;   // seg3: aud*a2
}

extern "C" void kernel_launch(void* const* d_in, const int* in_sizes, int n_in,
                              void* d_out, int out_size, void* d_ws, size_t ws_size,
                              hipStream_t stream){
  const float* aud = (const float*)d_in[0];   // fp32 inputs (verified round 4)
  const float* sem = (const float*)d_in[1];
  const float* W   = (const float*)d_in[2];
  // d_in[3] (bias) cancels in both softmaxes.
  float* out = (float*)d_out;                 // fp32 output (verified round 4)
  unsigned short* outw = (unsigned short*)d_out;

  // ws: ~329 KB
  float* ws    = (float*)d_ws;
  float* m_ws  = ws;                                   // 32768 f (128 KB)
  float* colB  = m_ws + (size_t)BSZ * TT;              // 32768 f (128 KB)
  float* a2_ws = colB + (size_t)BSZ * NSEM;            // 2048 f  (8 KB, unused now)
  float* pmax  = a2_ws + BSZ * DIM;                    // 128 f
  float* gpart = pmax + 128;                           // 128 f
  float* part  = gpart + 128;                          // 16384 f (64 KB)

  prep_kernel <<<512, 256, 0, stream>>>(sem, W, colB, outw);
  flash_kernel<<<512, 512, 0, stream>>>(aud, W, colB, m_ws, out, outw);
  bw1_kernel  <<<128, 256, 0, stream>>>(m_ws, pmax);
  bw2_kernel  <<<128, 256, 0, stream>>>(aud, m_ws, pmax, gpart, part);
  epi_kernel  <<<(BSZ * TT * 16) / 256, 256, 0, stream>>>(aud, gpart, part, out);
}

// Round 9
// 248.202 us; speedup vs baseline: 1.5012x; 1.5012x over previous
//
#include <hip/hip_runtime.h>
#include <stdint.h>

#define BSZ 16
#define TT  2048
#define NSEM 2048
#define DIM 128
#define ORS 1024          // shorts per output row (512 floats)
#define PSTR 68           // pbuf row stride in shorts (136B -> bank-stagger, measured 0 conflicts)
#define LOG2E 1.4426950408889634f
#define LN2   0.6931471805599453f

typedef __attribute__((ext_vector_type(8))) short short8;
typedef __attribute__((ext_vector_type(4))) float floatx4;

__device__ __forceinline__ unsigned short f2bf(float f){       // RNE
  unsigned u = __float_as_uint(f);
  return (unsigned short)((u + 0x7fffu + ((u >> 16) & 1u)) >> 16);
}
__device__ __forceinline__ unsigned pkbf(float a, float b){    // 2xf32 -> packed bf16 (RNE, HW)
  unsigned r;
  asm("v_cvt_pk_bf16_f32 %0, %1, %2" : "=v"(r) : "v"(a), "v"(b));
  return r;
}
__device__ __forceinline__ float e2(float x){                  // 2^x, single v_exp
#if __has_builtin(__builtin_amdgcn_exp2f)
  return __builtin_amdgcn_exp2f(x);
#else
  return exp2f(x);
#endif
}
__device__ __forceinline__ void ld8f(const float* p, float* v){
  floatx4 a = *(const floatx4*)p;
  floatx4 b = *(const floatx4*)(p + 4);
  v[0]=a[0]; v[1]=a[1]; v[2]=a[2]; v[3]=a[3];
  v[4]=b[0]; v[5]=b[1]; v[6]=b[2]; v[7]=b[3];
}

// Staging layout (in out buffer, shorts [512,1024) of rows b*TT + c, 1KB each):
//   KST chunk cK = nblk*4 + kc            (cK in [0,512))   : [quad][l15][8] = K[nblk*16+l15][kc*32+quad*8+j]
//   VST chunk cV = 512 + ntile*16 + kt*8 + dc (cV in [512,1024)) : [quad][l15][8] = V[ntile*64+kt*32+quad*8+j][dc*16+l15]
// One chunk == one coalesced 1KB wave access (16B/lane).

// ---------------- kernel 1: prep ----------------
// grid 512 (b = bx>>5, n0 = (bx&31)*64), 256 thr. colB pre-scaled by LOG2E (exp2 domain).
__global__ __launch_bounds__(256) void prep_kernel(const float* __restrict__ sem,
                                                   const float* __restrict__ W,
                                                   float* __restrict__ colB,
                                                   unsigned short* __restrict__ outw){
  __shared__ unsigned short tile[DIM * 72];        // [d][n] bf16, stride 72 (144B, 16B-mult)
  const int tid = threadIdx.x;
  const int b  = blockIdx.x >> 5;
  const int n0 = (blockIdx.x & 31) * 64;

  // phase 1: row r (64 rows), col chunk c (32 cols)
  const int r = tid >> 2, cc = tid & 3, c = cc * 32;
  const float* src = sem + ((size_t)(b * NSEM + n0 + r)) * DIM + c;
  float v[32];
  ld8f(src, v); ld8f(src + 8, v + 8); ld8f(src + 16, v + 16); ld8f(src + 24, v + 24);
  alignas(16) unsigned short bf[32];
  float cpart = 0.f;
  #pragma unroll
  for (int j = 0; j < 32; ++j){
    bf[j] = f2bf(v[j]);
    cpart += v[j] * W[DIM + c + j];                // w2 dot partial
  }
  // KST write: chunk (nblk, kc=cc), row l15 = r&15. 4 x 16B at stride 256B.
  {
    const int nblk = (n0 >> 4) + (r >> 4);
    const int l15r = r & 15;
    unsigned short* base = outw + ((size_t)(b * TT + nblk * 4 + cc)) * ORS + 512;
    const uint4* s4 = (const uint4*)bf;
    #pragma unroll
    for (int q = 0; q < 4; ++q)
      *(uint4*)(base + q * 128 + l15r * 8) = s4[q];
  }
  // LDS transpose stage
  #pragma unroll
  for (int j = 0; j < 32; ++j) tile[(c + j) * 72 + r] = bf[j];
  // colB reduce over the 4 col-chunks (lanes differing in bits 0..1)
  cpart += __shfl_xor(cpart, 1);
  cpart += __shfl_xor(cpart, 2);
  if (cc == 0) colB[b * NSEM + n0 + r] = cpart * LOG2E;   // exp2 domain
  __syncthreads();

  // phase 2: VST write. kt = tid>>7 (2), dc = (tid>>4)&7 (8), l15 = tid&15.
  {
    const int kt = tid >> 7, dc = (tid >> 4) & 7, l15 = tid & 15;
    const int d = dc * 16 + l15;
    const int ntile = n0 >> 6;
    unsigned short* base = outw + ((size_t)(b * TT + 512 + ntile * 16 + kt * 8 + dc)) * ORS + 512;
    #pragma unroll
    for (int q = 0; q < 4; ++q){
      uint4 tv = *(const uint4*)&tile[d * 72 + kt * 32 + q * 8];
      *(uint4*)(base + q * 128 + l15 * 8) = tv;
    }
  }
}

// ---------------- kernel 2: flash attention, n-split x2, all-direct K/V, no loop barriers ----
// grid 1024 (b = bx>>6, 32-row t-block), 256 thr = 4 waves: tg = wv&1 (16 t-rows),
// h = wv>>1 (n-half: [h*1024, h*1024+1024), 16 iters of 64 n). K and V load DIRECT
// from the coalesced staging chunks (L2/L3-resident, 1KB per wave-instruction).
// Waves fully decoupled in the loop (wave-private pbuf, no __syncthreads).
// Swapped QK -> row-local softmax in exp2 domain; cvt_pk P pack; defer-max.
// End: single barrier + pairwise half-merge (h1 -> h0) via LDS.
// __launch_bounds__(256,3): VGPR cap ~168 >= ~155 peak live -> no spills, 3 waves/SIMD.
__global__ __launch_bounds__(256, 3) void flash_kernel(const float* __restrict__ aud,
                                                    const float* __restrict__ W,
                                                    const float* __restrict__ colB,
                                                    float* __restrict__ m_ws,
                                                    float* __restrict__ outf,
                                                    const unsigned short* __restrict__ outw){
  __shared__ alignas(16) unsigned short pbuf[4][16 * PSTR];   // per-wave P staging, 8704 B
  __shared__ alignas(16) float Obuf[2][16][132];              // merge slices (tg), 16896 B
  __shared__ float mlbuf[2][3][16];                           // m,l,m_true per tg, 384 B

  const int tid  = threadIdx.x;
  const int wv   = tid >> 6;
  const int lane = tid & 63;
  const int quad = lane >> 4;
  const int l15  = lane & 15;
  const int tg   = wv & 1;                                    // t-group within block
  const int h    = wv >> 1;                                   // n-half
  const int b    = blockIdx.x >> 6;
  const int t0w  = (blockIdx.x & 63) * 32 + tg * 16;          // this wave's 16 rows

  // per-lane global staging base (shorts [512,1024) of rows b*TT + c)
  const unsigned short* stage = outw + (size_t)b * TT * ORS + 512 + lane * 8;

  // q A-frags (aud*w3*log2e -> bf16, exp2 domain) + rowA partial (fp32 dot aud,w1)
  const float* audRow = aud + ((size_t)b * TT + t0w + l15) * DIM;
  short8 qf[4];
  float rowA_part = 0.f;
  #pragma unroll
  for (int kc = 0; kc < 4; ++kc){
    int d0 = kc * 32 + quad * 8;
    float av[8], w3v[8], w1v[8];
    ld8f(audRow + d0, av);
    ld8f(W + 2 * DIM + d0, w3v);
    ld8f(W + d0, w1v);
    alignas(16) unsigned short tmp[8];
    #pragma unroll
    for (int j = 0; j < 8; ++j){
      tmp[j] = f2bf(av[j] * (w3v[j] * LOG2E));
      rowA_part += av[j] * w1v[j];
    }
    qf[kc] = *(const short8*)tmp;
  }
  rowA_part += __shfl_xor(rowA_part, 16);
  rowA_part += __shfl_xor(rowA_part, 32);   // full-d dot for row t0w + l15, replicated

  float m_run = -1e30f, l_run = 0.f;        // per-lane: row t = t0w + l15 (exp2 domain)
  float m_true = -1e30f;                    // exact running max (exp2 domain)
  floatx4 o[8];
  #pragma unroll
  for (int dc = 0; dc < 8; ++dc){
    #pragma unroll
    for (int r = 0; r < 4; ++r) o[dc][r] = 0.f;
  }

  const float* colBb = colB + b * NSEM;
  unsigned short* pb = &pbuf[wv][0];

  for (int it = 0; it < 16; ++it){
    const int nt = h * 16 + it;             // global 64-n tile index
    const int n0 = nt * 64;
    const unsigned short* stK = stage + (size_t)(nt * 16) * ORS;
    const unsigned short* stV = stage + (size_t)(512 + nt * 16) * ORS;

    // ---- V batch 0: issued first, consumed at PV (full-iteration latency window) ----
    short8 vf0[8];
    #pragma unroll
    for (int i = 0; i < 8; ++i) vf0[i] = *(const short8*)(stV + (size_t)i * ORS);
    // colB addends
    floatx4 cbv[4];
    #pragma unroll
    for (int s = 0; s < 4; ++s) cbv[s] = *(const floatx4*)(colBb + n0 + s*16 + quad*4);
    __builtin_amdgcn_sched_barrier(0);      // pin: vf0/colB issue before QK consumes VMEM queue

    // ---- QK swapped: sacc[s] = K_frag x Q -> S[n=quad*4+r][t=l15] (exp2 domain) ----
    // K frags inline: compiler windows them; 3 waves/SIMD cover the exposed latency.
    floatx4 sacc[4];
    #pragma unroll
    for (int s = 0; s < 4; ++s){ sacc[s][0]=0.f; sacc[s][1]=0.f; sacc[s][2]=0.f; sacc[s][3]=0.f; }
    #pragma unroll
    for (int s = 0; s < 4; ++s){
      #pragma unroll
      for (int kc = 0; kc < 4; ++kc){
        short8 kf = *(const short8*)(stK + (size_t)(s*4 + kc) * ORS);
        sacc[s] = __builtin_amdgcn_mfma_f32_16x16x32_bf16(kf, qf[kc], sacc[s], 0, 0, 0);
      }
    }

    // ---- V batch 1: issued here, lands under softmax ----
    short8 vf1[8];
    #pragma unroll
    for (int i = 0; i < 8; ++i) vf1[i] = *(const short8*)(stV + (size_t)(8 + i) * ORS);
    __builtin_amdgcn_sched_barrier(0);

    // ---- online softmax, row-local (t = l15), defer-max THR=8 (log2 units) ----
    float v[4][4];
    #pragma unroll
    for (int s = 0; s < 4; ++s){
      #pragma unroll
      for (int r = 0; r < 4; ++r) v[s][r] = sacc[s][r] + cbv[s][r];
    }
    float mq[4];
    #pragma unroll
    for (int s = 0; s < 4; ++s)
      mq[s] = fmaxf(fmaxf(v[s][0], v[s][1]), fmaxf(v[s][2], v[s][3]));
    float mx = fmaxf(fmaxf(mq[0], mq[1]), fmaxf(mq[2], mq[3]));
    mx = fmaxf(mx, __shfl_xor(mx, 16));
    mx = fmaxf(mx, __shfl_xor(mx, 32));
    m_true = fmaxf(m_true, mx);

    const bool defer = (__all(mx - m_run <= 8.0f) != 0);   // wave-uniform
    float al = 1.0f;
    if (!defer){
      float mnew = fmaxf(m_run, mx);
      al = e2(m_run - mnew);
      m_run = mnew;
    }
    float e[4][4];
    #pragma unroll
    for (int s = 0; s < 4; ++s){
      #pragma unroll
      for (int r = 0; r < 4; ++r) e[s][r] = e2(v[s][r] - m_run);
    }
    float sq[4];
    #pragma unroll
    for (int s = 0; s < 4; ++s)
      sq[s] = (e[s][0] + e[s][1]) + (e[s][2] + e[s][3]);
    float ps = (sq[0] + sq[1]) + (sq[2] + sq[3]);
    ps += __shfl_xor(ps, 16);
    ps += __shfl_xor(ps, 32);
    l_run = l_run * al + ps;

    // P staging (R7 layout, measured 0 conflicts): hw cvt_pk pairs -> 2x ds_write_b32
    #pragma unroll
    for (int s = 0; s < 4; ++s){
      unsigned u0 = pkbf(e[s][0], e[s][1]);
      unsigned u1 = pkbf(e[s][2], e[s][3]);
      unsigned short* pr = pb + l15 * PSTR + s * 16 + quad * 4;
      *(unsigned*)(pr)     = u0;
      *(unsigned*)(pr + 2) = u1;
    }

    // o-rescale only when max actually moved (rare after warm-up)
    if (!defer){
      float aB[4];
      #pragma unroll
      for (int r = 0; r < 4; ++r) aB[r] = __shfl(al, quad*4 + r);
      #pragma unroll
      for (int dc = 0; dc < 8; ++dc){
        #pragma unroll
        for (int r = 0; r < 4; ++r) o[dc][r] *= aB[r];
      }
    }

    // wave-local LDS visibility (in-order DS per wave; just drain writes)
    asm volatile("s_waitcnt lgkmcnt(0)" ::: "memory");
    short8 pf0 = *(const short8*)(pb + l15 * PSTR + quad * 8);
    short8 pf1 = *(const short8*)(pb + l15 * PSTR + 32 + quad * 8);

    // ---- PV: O += P . sem ----
    #pragma unroll
    for (int dc = 0; dc < 8; ++dc)
      o[dc] = __builtin_amdgcn_mfma_f32_16x16x32_bf16(pf0, vf0[dc], o[dc], 0, 0, 0);
    #pragma unroll
    for (int dc = 0; dc < 8; ++dc)
      o[dc] = __builtin_amdgcn_mfma_f32_16x16x32_bf16(pf1, vf1[dc], o[dc], 0, 0, 0);
  }

  // ---- half-merge: h1 publishes (O, m, l, m_true); h0 merges + epilogue ----
  if (h == 1){
    #pragma unroll
    for (int dc = 0; dc < 8; ++dc){
      #pragma unroll
      for (int r = 0; r < 4; ++r)
        Obuf[tg][quad * 4 + r][dc * 16 + l15] = o[dc][r];
    }
    if (quad == 0){
      mlbuf[tg][0][l15] = m_run;
      mlbuf[tg][1][l15] = l_run;
      mlbuf[tg][2][l15] = m_true;
    }
  }
  __syncthreads();
  if (h == 0){
    float mp  = mlbuf[tg][0][l15];
    float lp  = mlbuf[tg][1][l15];
    float mtp = mlbuf[tg][2][l15];
    float M  = fmaxf(m_run, mp);
    float sA = e2(m_run - M);
    float sB = e2(mp - M);
    float lm = l_run * sA + lp * sB;
    float mt = fmaxf(m_true, mtp);
    float rl = 1.0f / lm;
    float fa = sA * rl, fb = sB * rl;
    float fA[4], fB[4];
    #pragma unroll
    for (int r = 0; r < 4; ++r){ fA[r] = __shfl(fa, quad*4 + r); fB[r] = __shfl(fb, quad*4 + r); }
    float* outB = outf + ((size_t)b * TT + t0w) * 512 + 128;
    #pragma unroll
    for (int dc = 0; dc < 8; ++dc){
      #pragma unroll
      for (int r = 0; r < 4; ++r){
        float op = Obuf[tg][quad * 4 + r][dc * 16 + l15];
        outB[(size_t)(quad*4 + r) * 512 + dc*16 + l15] = o[dc][r] * fA[r] + op * fB[r];
      }
    }
    if (quad == 0)
      m_ws[(size_t)b * TT + t0w + l15] = mt * LN2 + rowA_part;   // back to natural domain
  }
}

// ---------------- kernel 3a: per-chunk max of m ----------------
__global__ __launch_bounds__(256) void bw1_kernel(const float* __restrict__ m_ws,
                                                  float* __restrict__ pmax){
  __shared__ float sA[4];
  const int b = blockIdx.x >> 3, ch = blockIdx.x & 7, tid = threadIdx.x;
  float v = m_ws[(size_t)b * TT + ch * 256 + tid];
  #pragma unroll
  for (int off = 1; off < 64; off <<= 1) v = fmaxf(v, __shfl_xor(v, off));
  if ((tid & 63) == 0) sA[tid >> 6] = v;
  __syncthreads();
  if (tid == 0)
    pmax[blockIdx.x] = fmaxf(fmaxf(sA[0], sA[1]), fmaxf(sA[2], sA[3]));
}

// ---------------- kernel 3b: partial exp-sum + partial a2 ----------------
__global__ __launch_bounds__(256) void bw2_kernel(const float* __restrict__ aud,
                                                  const float* __restrict__ m_ws,
                                                  const float* __restrict__ pmax,
                                                  float* __restrict__ gpart,
                                                  float* __restrict__ part){
  __shared__ float wbuf[256];
  __shared__ float red[16 * 128];
  __shared__ float gs4[4];
  const int b = blockIdx.x >> 3, ch = blockIdx.x & 7, tid = threadIdx.x;

  float gmax = pmax[b * 8];
  #pragma unroll
  for (int i = 1; i < 8; ++i) gmax = fmaxf(gmax, pmax[b * 8 + i]);

  float w = __expf(m_ws[(size_t)b * TT + ch * 256 + tid] - gmax);
  wbuf[tid] = w;
  float sm = w;
  #pragma unroll
  for (int off = 1; off < 64; off <<= 1) sm += __shfl_xor(sm, off);
  if ((tid & 63) == 0) gs4[tid >> 6] = sm;
  __syncthreads();
  if (tid == 0) gpart[blockIdx.x] = (gs4[0] + gs4[1]) + (gs4[2] + gs4[3]);

  const int dg = tid & 15, q = tid >> 4;
  float acc[8] = {0,0,0,0,0,0,0,0};
  const float* ab = aud + ((size_t)b * TT + ch * 256 + q * 16) * DIM + dg * 8;
  for (int i = 0; i < 16; ++i){
    float av[8];
    ld8f(ab + (size_t)i * DIM, av);
    float wt = wbuf[q * 16 + i];
    #pragma unroll
    for (int j = 0; j < 8; ++j) acc[j] += wt * av[j];
  }
  #pragma unroll
  for (int j = 0; j < 8; ++j) red[q * 128 + dg * 8 + j] = acc[j];
  __syncthreads();
  if (tid < 128){
    float s = 0.f;
    #pragma unroll
    for (int q2 = 0; q2 < 16; ++q2) s += red[q2 * 128 + tid];
    part[(size_t)blockIdx.x * 128 + tid] = s;
  }
}

// ---------------- kernel 4: read seg1 (h) + bw partials, write seg0/2/3 ----------------
// bw3 fused: per block (fixed b) reduce part/gpart -> a2[128] in LDS once.
__global__ __launch_bounds__(256) void epi_kernel(const float* __restrict__ aud,
                                                  const float* __restrict__ gpart,
                                                  const float* __restrict__ part,
                                                  float* __restrict__ out){
  __shared__ float a2s[DIM];
  int id = blockIdx.x * 256 + threadIdx.x;        // BSZ*TT*16
  int c = id & 15;
  int t = (id >> 4) & (TT - 1);
  int b = id >> 15;
  size_t row = (size_t)b * TT + t;

  if (threadIdx.x < 128){
    const int d = threadIdx.x;
    float s = 0.f, g = 0.f;
    #pragma unroll
    for (int ch = 0; ch < 8; ++ch){
      s += part[(size_t)(b * 8 + ch) * 128 + d];
      g += gpart[b * 8 + ch];
    }
    a2s[d] = s / g;
  }
  __syncthreads();

  float av[8], gv[8], hv[8];
  ld8f(aud + row * DIM + c * 8, av);
  ld8f(out + row * 512 + 128 + c * 8, hv);        // h (seg1)
  #pragma unroll
  for (int j = 0; j < 8; ++j) gv[j] = a2s[c * 8 + j];

  floatx4 o0a, o0b, o2a, o2b, o3a, o3b;
  #pragma unroll
  for (int j = 0; j < 4; ++j){
    o0a[j] = av[j];           o0b[j] = av[4+j];
    o2a[j] = av[j]*hv[j];     o2b[j] = av[4+j]*hv[4+j];
    o3a[j] = av[j]*gv[j];     o3b[j] = av[4+j]*gv[4+j];
  }
  float* ob = out + row * 512 + c * 8;
  *(floatx4*)(ob)       = o0a;  *(floatx4*)(ob + 4)   = o0b;   // seg0: aud
  *(floatx4*)(ob + 256) = o2a;  *(floatx4*)(ob + 260) = o2b;   // seg2: aud*h
  *(floatx4*)(ob + 384) = o3a;  *(floatx4*)(ob + 388) = o3b;   // seg3: aud*a2
}

extern "C" void kernel_launch(void* const* d_in, const int* in_sizes, int n_in,
                              void* d_out, int out_size, void* d_ws, size_t ws_size,
                              hipStream_t stream){
  const float* aud = (const float*)d_in[0];   // fp32 inputs (verified round 4)
  const float* sem = (const float*)d_in[1];
  const float* W   = (const float*)d_in[2];
  // d_in[3] (bias) cancels in both softmaxes.
  float* out = (float*)d_out;                 // fp32 output (verified round 4)
  unsigned short* outw = (unsigned short*)d_out;

  // ws: ~329 KB
  float* ws    = (float*)d_ws;
  float* m_ws  = ws;                                   // 32768 f (128 KB)
  float* colB  = m_ws + (size_t)BSZ * TT;              // 32768 f (128 KB)
  float* a2_ws = colB + (size_t)BSZ * NSEM;            // 2048 f  (8 KB, unused now)
  float* pmax  = a2_ws + BSZ * DIM;                    // 128 f
  float* gpart = pmax + 128;                           // 128 f
  float* part  = gpart + 128;                          // 16384 f (64 KB)

  prep_kernel <<<512, 256, 0, stream>>>(sem, W, colB, outw);
  flash_kernel<<<1024, 256, 0, stream>>>(aud, W, colB, m_ws, out, outw);
  bw1_kernel  <<<128, 256, 0, stream>>>(m_ws, pmax);
  bw2_kernel  <<<128, 256, 0, stream>>>(aud, m_ws, pmax, gpart, part);
  epi_kernel  <<<(BSZ * TT * 16) / 256, 256, 0, stream>>>(aud, gpart, part, out);
}

// Round 11
// 215.012 us; speedup vs baseline: 1.7329x; 1.1544x over previous
//
#include <hip/hip_runtime.h>
#include <stdint.h>

#define BSZ 16
#define TT  2048
#define NSEM 2048
#define DIM 128
#define ORS 1024          // shorts per output row (512 floats)
#define PSTR 68           // pbuf row stride in shorts (136B -> bank-stagger, measured 0 conflicts)
#define LOG2E 1.4426950408889634f
#define LN2   0.6931471805599453f

typedef __attribute__((ext_vector_type(8))) short short8;
typedef __attribute__((ext_vector_type(4))) float floatx4;

__device__ __forceinline__ unsigned short f2bf(float f){       // RNE
  unsigned u = __float_as_uint(f);
  return (unsigned short)((u + 0x7fffu + ((u >> 16) & 1u)) >> 16);
}
__device__ __forceinline__ unsigned pkbf(float a, float b){    // 2xf32 -> packed bf16 (RNE, HW)
  unsigned r;
  asm("v_cvt_pk_bf16_f32 %0, %1, %2" : "=v"(r) : "v"(a), "v"(b));
  return r;
}
__device__ __forceinline__ float e2(float x){                  // 2^x, single v_exp
#if __has_builtin(__builtin_amdgcn_exp2f)
  return __builtin_amdgcn_exp2f(x);
#else
  return exp2f(x);
#endif
}
__device__ __forceinline__ void ld8f(const float* p, float* v){
  floatx4 a = *(const floatx4*)p;
  floatx4 b = *(const floatx4*)(p + 4);
  v[0]=a[0]; v[1]=a[1]; v[2]=a[2]; v[3]=a[3];
  v[4]=b[0]; v[5]=b[1]; v[6]=b[2]; v[7]=b[3];
}
// async global->LDS: 64 lanes x 16B; LDS dest is wave-uniform base + lane*16.
__device__ __forceinline__ void gload_lds16(const unsigned short* g, unsigned short* l){
  __builtin_amdgcn_global_load_lds((const __attribute__((address_space(1))) void*)g,
                                   (__attribute__((address_space(3))) void*)l, 16, 0, 0);
}

// Staging layout (in out buffer, shorts [512,1024) of rows b*TT + c, 1KB each):
//   KST chunk cK (rows 0..511)   : [quad][l15][8] = K[nblk*16+l15][kc*32+quad*8+j]
//   VST chunk cV (rows 512..1023): [quad][l15][8] = V[ntile*64+kt*32+quad*8+j][dc*16+l15]
// Partials (flash->merge), rows 1024..2047 of each b:
//   h=1 O      -> floats 256 + (t&1)*128 + d      (fills [256,512) exactly)
//   m/l/mt x2h -> floats (t&1)*8 + h*4 .. +3      (seg0 head, free until epi)
//   h=0 O      -> seg1 floats [128,256) of own rows (its final home).

// ---------------- kernel 1: prep ----------------
// grid 512 (b = bx>>5, n0 = (bx&31)*64), 256 thr. colB pre-scaled by LOG2E (exp2 domain).
__global__ __launch_bounds__(256) void prep_kernel(const float* __restrict__ sem,
                                                   const float* __restrict__ W,
                                                   float* __restrict__ colB,
                                                   unsigned short* __restrict__ outw){
  __shared__ unsigned short tile[DIM * 72];        // [d][n] bf16, stride 72 (144B, 16B-mult)
  const int tid = threadIdx.x;
  const int b  = blockIdx.x >> 5;
  const int n0 = (blockIdx.x & 31) * 64;

  // phase 1: row r (64 rows), col chunk c (32 cols)
  const int r = tid >> 2, cc = tid & 3, c = cc * 32;
  const float* src = sem + ((size_t)(b * NSEM + n0 + r)) * DIM + c;
  float v[32];
  ld8f(src, v); ld8f(src + 8, v + 8); ld8f(src + 16, v + 16); ld8f(src + 24, v + 24);
  alignas(16) unsigned short bf[32];
  float cpart = 0.f;
  #pragma unroll
  for (int j = 0; j < 32; ++j){
    bf[j] = f2bf(v[j]);
    cpart += v[j] * W[DIM + c + j];                // w2 dot partial
  }
  // KST write: chunk (nblk, kc=cc), row l15 = r&15. 4 x 16B at stride 256B.
  {
    const int nblk = (n0 >> 4) + (r >> 4);
    const int l15r = r & 15;
    unsigned short* base = outw + ((size_t)(b * TT + nblk * 4 + cc)) * ORS + 512;
    const uint4* s4 = (const uint4*)bf;
    #pragma unroll
    for (int q = 0; q < 4; ++q)
      *(uint4*)(base + q * 128 + l15r * 8) = s4[q];
  }
  // LDS transpose stage
  #pragma unroll
  for (int j = 0; j < 32; ++j) tile[(c + j) * 72 + r] = bf[j];
  // colB reduce over the 4 col-chunks (lanes differing in bits 0..1)
  cpart += __shfl_xor(cpart, 1);
  cpart += __shfl_xor(cpart, 2);
  if (cc == 0) colB[b * NSEM + n0 + r] = cpart * LOG2E;   // exp2 domain
  __syncthreads();

  // phase 2: VST write. kt = tid>>7 (2), dc = (tid>>4)&7 (8), l15 = tid&15.
  {
    const int kt = tid >> 7, dc = (tid >> 4) & 7, l15 = tid & 15;
    const int d = dc * 16 + l15;
    const int ntile = n0 >> 6;
    unsigned short* base = outw + ((size_t)(b * TT + 512 + ntile * 16 + kt * 8 + dc)) * ORS + 512;
    #pragma unroll
    for (int q = 0; q < 4; ++q){
      uint4 tv = *(const uint4*)&tile[d * 72 + kt * 32 + q * 8];
      *(uint4*)(base + q * 128 + l15 * 8) = tv;
    }
  }
}

// ---------------- kernel 2: flash attention (R7 loop, grid n-split x2) ----------------
// grid 1024: b = bx>>6; tb = (bx&63)>>1 (64-row t-block); h = bx&1 (n-half).
// 256 thr = 4 waves; wave wv owns 16 t-rows; block iterates its half's 16 n-tiles.
// K: LDS double-buffered via global_load_lds; V: direct from L2 (windowed regs).
// Writes UNNORMALIZED partial (O, m_run, l_run, mt) -> merged by merge_kernel.
// LDS 41472 B, VGPR ~92 -> 3 blocks/CU resident (12 waves/CU), vs R7's grid-capped 2.
__global__ __launch_bounds__(256, 2) void flash_kernel(const float* __restrict__ aud,
                                                    const float* __restrict__ W,
                                                    const float* __restrict__ colB,
                                                    float* __restrict__ outf,
                                                    const unsigned short* __restrict__ outw){
  __shared__ alignas(16) unsigned short kvt[2][16][512];      // 2 bufs x 16 K-chunks x 1KB = 32 KB
  __shared__ alignas(16) unsigned short pbuf[4][16 * PSTR];   // per-wave P staging, 8704 B

  const int tid  = threadIdx.x;
  const int wv   = tid >> 6;
  const int lane = tid & 63;
  const int quad = lane >> 4;
  const int l15  = lane & 15;
  const int b    = blockIdx.x >> 6;
  const int sub  = blockIdx.x & 63;
  const int tb   = sub >> 1;
  const int h    = sub & 1;                                   // n-half
  const int t0w  = tb * 64 + wv * 16;                         // this wave's 16 rows

  // per-lane global staging base (shorts [512,1024) of rows b*TT + c)
  const unsigned short* stage = outw + (size_t)b * TT * ORS + 512 + lane * 8;

  // prologue: stage K tile 0 of this half (chunks j = wv*4..wv*4+3 of tile h*16)
  #pragma unroll
  for (int jj = 0; jj < 4; ++jj){
    const int j = wv * 4 + jj;
    gload_lds16(stage + (size_t)(h * 256 + j) * ORS, &kvt[0][j][0]);
  }

  // q A-frags (aud*w3*log2e -> bf16, exp2 domain) + rowA partial (fp32 dot aud,w1)
  const float* audRow = aud + ((size_t)b * TT + t0w + l15) * DIM;
  short8 qf[4];
  float rowA_part = 0.f;
  #pragma unroll
  for (int kc = 0; kc < 4; ++kc){
    int d0 = kc * 32 + quad * 8;
    float av[8], w3v[8], w1v[8];
    ld8f(audRow + d0, av);
    ld8f(W + 2 * DIM + d0, w3v);
    ld8f(W + d0, w1v);
    alignas(16) unsigned short tmp[8];
    #pragma unroll
    for (int j = 0; j < 8; ++j){
      tmp[j] = f2bf(av[j] * (w3v[j] * LOG2E));
      rowA_part += av[j] * w1v[j];
    }
    qf[kc] = *(const short8*)tmp;
  }
  rowA_part += __shfl_xor(rowA_part, 16);
  rowA_part += __shfl_xor(rowA_part, 32);   // full-d dot for row t0w + l15, replicated

  float m_run = -1e30f, l_run = 0.f;        // per-lane: row t = t0w + l15 (exp2 domain)
  float m_true = -1e30f;                    // exact running max (exp2 domain)
  floatx4 o[8];
  #pragma unroll
  for (int dc = 0; dc < 8; ++dc){
    #pragma unroll
    for (int r = 0; r < 4; ++r) o[dc][r] = 0.f;
  }

  const float* colBb = colB + b * NSEM;
  unsigned short* pb = &pbuf[wv][0];

  __syncthreads();                                  // K tile 0 staged

  for (int it = 0; it < 16; ++it){
    const int nt = h * 16 + it;             // global 64-n tile index
    const int n0 = nt * 64;

    // ---- V frags: direct global loads (issued FIRST so their waitcnt doesn't drain DMAs) ----
    const int cV = 512 + nt * 16;
    short8 vf[16];
    #pragma unroll
    for (int i = 0; i < 16; ++i) vf[i] = *(const short8*)(stage + (size_t)(cV + i) * ORS);

    // ---- prefetch K tile it+1 (DMA, no regs) ----
    if (it + 1 < 16){
      #pragma unroll
      for (int jj = 0; jj < 4; ++jj){
        const int j = wv * 4 + jj;
        gload_lds16(stage + (size_t)(h * 256 + (it + 1) * 16 + j) * ORS,
                    &kvt[(it + 1) & 1][j][0]);
      }
    }
    __builtin_amdgcn_sched_barrier(0);      // pin: all VMEM issued before compute

    const unsigned short* kvb = &kvt[it & 1][0][0] + lane * 8;

    // colB addends: per lane n = n0 + s*16 + quad*4 + r
    floatx4 cbv[4];
    #pragma unroll
    for (int s = 0; s < 4; ++s) cbv[s] = *(const floatx4*)(colBb + n0 + s*16 + quad*4);

    // ---- QK swapped: sacc[s] = K_frag x Q -> S[n=quad*4+r][t=l15] (exp2 domain) ----
    floatx4 sacc[4];
    #pragma unroll
    for (int s = 0; s < 4; ++s){ sacc[s][0]=0.f; sacc[s][1]=0.f; sacc[s][2]=0.f; sacc[s][3]=0.f; }
    #pragma unroll
    for (int s = 0; s < 4; ++s){
      #pragma unroll
      for (int kc = 0; kc < 4; ++kc){
        short8 kf = *(const short8*)(kvb + (s*4 + kc) * 512);
        sacc[s] = __builtin_amdgcn_mfma_f32_16x16x32_bf16(kf, qf[kc], sacc[s], 0, 0, 0);
      }
    }

    // ---- online softmax, row-local (t = l15), defer-max THR=8 (log2 units) ----
    float v[4][4];
    #pragma unroll
    for (int s = 0; s < 4; ++s){
      #pragma unroll
      for (int r = 0; r < 4; ++r) v[s][r] = sacc[s][r] + cbv[s][r];
    }
    float mq[4];
    #pragma unroll
    for (int s = 0; s < 4; ++s)
      mq[s] = fmaxf(fmaxf(v[s][0], v[s][1]), fmaxf(v[s][2], v[s][3]));
    float mx = fmaxf(fmaxf(mq[0], mq[1]), fmaxf(mq[2], mq[3]));
    mx = fmaxf(mx, __shfl_xor(mx, 16));
    mx = fmaxf(mx, __shfl_xor(mx, 32));
    m_true = fmaxf(m_true, mx);

    const bool defer = (__all(mx - m_run <= 8.0f) != 0);   // wave-uniform
    float al = 1.0f;
    if (!defer){
      float mnew = fmaxf(m_run, mx);
      al = e2(m_run - mnew);
      m_run = mnew;
    }
    float e[4][4];
    #pragma unroll
    for (int s = 0; s < 4; ++s){
      #pragma unroll
      for (int r = 0; r < 4; ++r) e[s][r] = e2(v[s][r] - m_run);
    }
    float sq[4];
    #pragma unroll
    for (int s = 0; s < 4; ++s)
      sq[s] = (e[s][0] + e[s][1]) + (e[s][2] + e[s][3]);
    float ps = (sq[0] + sq[1]) + (sq[2] + sq[3]);
    ps += __shfl_xor(ps, 16);
    ps += __shfl_xor(ps, 32);
    l_run = l_run * al + ps;

    // P staging (R7 layout, measured 0 conflicts): hw cvt_pk pairs -> 2x ds_write_b32
    #pragma unroll
    for (int s = 0; s < 4; ++s){
      unsigned u0 = pkbf(e[s][0], e[s][1]);
      unsigned u1 = pkbf(e[s][2], e[s][3]);
      unsigned short* pr = pb + l15 * PSTR + s * 16 + quad * 4;
      *(unsigned*)(pr)     = u0;
      *(unsigned*)(pr + 2) = u1;
    }

    // o-rescale only when max actually moved (rare after warm-up)
    if (!defer){
      float aB[4];
      #pragma unroll
      for (int r = 0; r < 4; ++r) aB[r] = __shfl(al, quad*4 + r);
      #pragma unroll
      for (int dc = 0; dc < 8; ++dc){
        #pragma unroll
        for (int r = 0; r < 4; ++r) o[dc][r] *= aB[r];
      }
    }

    // wave-local LDS visibility (in-order DS per wave; just drain writes)
    asm volatile("s_waitcnt lgkmcnt(0)" ::: "memory");
    short8 pf0 = *(const short8*)(pb + l15 * PSTR + quad * 8);
    short8 pf1 = *(const short8*)(pb + l15 * PSTR + 32 + quad * 8);

    // ---- PV: O += P . sem, V frags in regs ----
    #pragma unroll
    for (int kt = 0; kt < 2; ++kt){
      short8 pf = kt ? pf1 : pf0;
      #pragma unroll
      for (int dc = 0; dc < 8; ++dc)
        o[dc] = __builtin_amdgcn_mfma_f32_16x16x32_bf16(pf, vf[kt*8 + dc], o[dc], 0, 0, 0);
    }

    // tile boundary: K-buffer swap safety + DMA drain
    __syncthreads();
  }

  // ---- epilogue: write UNNORMALIZED partials ----
  // h=0 O -> seg1 (floats [128,256) of own rows).
  // h=1 O -> rows b*TT+1024+(t>>1), floats 256+(t&1)*128  (fills [256,512), no overlap).
  // (m_run, l_run, mt) both halves -> same rows, floats (t&1)*8 + h*4 (seg0 head, free).
  if (h == 0){
    float* outB = outf + ((size_t)b * TT + t0w) * 512 + 128;
    #pragma unroll
    for (int dc = 0; dc < 8; ++dc){
      #pragma unroll
      for (int r = 0; r < 4; ++r)
        outB[(size_t)(quad*4 + r) * 512 + dc*16 + l15] = o[dc][r];
    }
  } else {
    float* outB = outf + ((size_t)(b * TT + 1024 + (t0w >> 1))) * 512 + 256;
    #pragma unroll
    for (int dc = 0; dc < 8; ++dc){
      #pragma unroll
      for (int r = 0; r < 4; ++r)
        outB[(size_t)(quad*2 + (r >> 1)) * 512 + (r & 1) * 128 + dc*16 + l15] = o[dc][r];
    }
  }
  if (quad == 0){
    float* mlp = outf + ((size_t)(b * TT + 1024 + ((t0w + l15) >> 1))) * 512
               + (l15 & 1) * 8 + h * 4;
    mlp[0] = m_run;                          // exp2-domain stale max
    mlp[1] = l_run;                          // linear partial denom
    mlp[2] = m_true * LN2 + rowA_part;       // natural-domain exact max + rowA (for bw)
  }
}

// ---------------- kernel 2b: merge halves -> h (seg1) + m_ws ----------------
// grid 2048, 256 thr. id -> c (8-float d-chunk), t, b. In-place over seg1.
__global__ __launch_bounds__(256) void merge_kernel(float* __restrict__ out,
                                                    float* __restrict__ m_ws){
  int id = blockIdx.x * 256 + threadIdx.x;        // BSZ*TT*16
  int c = id & 15;
  int t = (id >> 4) & (TT - 1);
  int b = id >> 15;
  size_t row  = (size_t)b * TT + t;
  size_t mrow = (size_t)b * TT + 1024 + (t >> 1);
  int mo = t & 1;

  float O0[8], O1[8];
  ld8f(out + row * 512 + 128 + c * 8, O0);
  ld8f(out + mrow * 512 + 256 + mo * 128 + c * 8, O1);
  const float* mlp = out + mrow * 512 + mo * 8;
  float m0 = mlp[0], l0 = mlp[1], mt0 = mlp[2];
  float m1 = mlp[4], l1 = mlp[5], mt1 = mlp[6];

  float M  = fmaxf(m0, m1);
  float fA = e2(m0 - M), fB = e2(m1 - M);
  float rl = 1.0f / (l0 * fA + l1 * fB);
  fA *= rl; fB *= rl;

  floatx4 h0, h1;
  #pragma unroll
  for (int j = 0; j < 4; ++j){
    h0[j] = O0[j]   * fA + O1[j]   * fB;
    h1[j] = O0[4+j] * fA + O1[4+j] * fB;
  }
  float* dst = out + row * 512 + 128 + c * 8;
  *(floatx4*)(dst)     = h0;
  *(floatx4*)(dst + 4) = h1;
  if (c == 0) m_ws[row] = fmaxf(mt0, mt1);
}

// ---------------- kernel 3a: per-chunk max of m ----------------
__global__ __launch_bounds__(256) void bw1_kernel(const float* __restrict__ m_ws,
                                                  float* __restrict__ pmax){
  __shared__ float sA[4];
  const int b = blockIdx.x >> 3, ch = blockIdx.x & 7, tid = threadIdx.x;
  float v = m_ws[(size_t)b * TT + ch * 256 + tid];
  #pragma unroll
  for (int off = 1; off < 64; off <<= 1) v = fmaxf(v, __shfl_xor(v, off));
  if ((tid & 63) == 0) sA[tid >> 6] = v;
  __syncthreads();
  if (tid == 0)
    pmax[blockIdx.x] = fmaxf(fmaxf(sA[0], sA[1]), fmaxf(sA[2], sA[3]));
}

// ---------------- kernel 3b: partial exp-sum + partial a2 ----------------
__global__ __launch_bounds__(256) void bw2_kernel(const float* __restrict__ aud,
                                                  const float* __restrict__ m_ws,
                                                  const float* __restrict__ pmax,
                                                  float* __restrict__ gpart,
                                                  float* __restrict__ part){
  __shared__ float wbuf[256];
  __shared__ float red[16 * 128];
  __shared__ float gs4[4];
  const int b = blockIdx.x >> 3, ch = blockIdx.x & 7, tid = threadIdx.x;

  float gmax = pmax[b * 8];
  #pragma unroll
  for (int i = 1; i < 8; ++i) gmax = fmaxf(gmax, pmax[b * 8 + i]);

  float w = __expf(m_ws[(size_t)b * TT + ch * 256 + tid] - gmax);
  wbuf[tid] = w;
  float sm = w;
  #pragma unroll
  for (int off = 1; off < 64; off <<= 1) sm += __shfl_xor(sm, off);
  if ((tid & 63) == 0) gs4[tid >> 6] = sm;
  __syncthreads();
  if (tid == 0) gpart[blockIdx.x] = (gs4[0] + gs4[1]) + (gs4[2] + gs4[3]);

  const int dg = tid & 15, q = tid >> 4;
  float acc[8] = {0,0,0,0,0,0,0,0};
  const float* ab = aud + ((size_t)b * TT + ch * 256 + q * 16) * DIM + dg * 8;
  for (int i = 0; i < 16; ++i){
    float av[8];
    ld8f(ab + (size_t)i * DIM, av);
    float wt = wbuf[q * 16 + i];
    #pragma unroll
    for (int j = 0; j < 8; ++j) acc[j] += wt * av[j];
  }
  #pragma unroll
  for (int j = 0; j < 8; ++j) red[q * 128 + dg * 8 + j] = acc[j];
  __syncthreads();
  if (tid < 128){
    float s = 0.f;
    #pragma unroll
    for (int q2 = 0; q2 < 16; ++q2) s += red[q2 * 128 + tid];
    part[(size_t)blockIdx.x * 128 + tid] = s;
  }
}

// ---------------- kernel 4: read seg1 (h) + bw partials, write seg0/2/3 ----------------
// bw3 fused: per block (fixed b) reduce part/gpart -> a2[128] in LDS once.
__global__ __launch_bounds__(256) void epi_kernel(const float* __restrict__ aud,
                                                  const float* __restrict__ gpart,
                                                  const float* __restrict__ part,
                                                  float* __restrict__ out){
  __shared__ float a2s[DIM];
  int id = blockIdx.x * 256 + threadIdx.x;        // BSZ*TT*16
  int c = id & 15;
  int t = (id >> 4) & (TT - 1);
  int b = id >> 15;
  size_t row = (size_t)b * TT + t;

  if (threadIdx.x < 128){
    const int d = threadIdx.x;
    float s = 0.f, g = 0.f;
    #pragma unroll
    for (int ch = 0; ch < 8; ++ch){
      s += part[(size_t)(b * 8 + ch) * 128 + d];
      g += gpart[b * 8 + ch];
    }
    a2s[d] = s / g;
  }
  __syncthreads();

  float av[8], gv[8], hv[8];
  ld8f(aud + row * DIM + c * 8, av);
  ld8f(out + row * 512 + 128 + c * 8, hv);        // h (seg1, merged)
  #pragma unroll
  for (int j = 0; j < 8; ++j) gv[j] = a2s[c * 8 + j];

  floatx4 o0a, o0b, o2a, o2b, o3a, o3b;
  #pragma unroll
  for (int j = 0; j < 4; ++j){
    o0a[j] = av[j];           o0b[j] = av[4+j];
    o2a[j] = av[j]*hv[j];     o2b[j] = av[4+j]*hv[4+j];
    o3a[j] = av[j]*gv[j];     o3b[j] = av[4+j]*gv[4+j];
  }
  float* ob = out + row * 512 + c * 8;
  *(floatx4*)(ob)       = o0a;  *(floatx4*)(ob + 4)   = o0b;   // seg0: aud
  *(floatx4*)(ob + 256) = o2a;  *(floatx4*)(ob + 260) = o2b;   // seg2: aud*h
  *(floatx4*)(ob + 384) = o3a;  *(floatx4*)(ob + 388) = o3b;   // seg3: aud*a2
}

extern "C" void kernel_launch(void* const* d_in, const int* in_sizes, int n_in,
                              void* d_out, int out_size, void* d_ws, size_t ws_size,
                              hipStream_t stream){
  const float* aud = (const float*)d_in[0];   // fp32 inputs (verified round 4)
  const float* sem = (const float*)d_in[1];
  const float* W   = (const float*)d_in[2];
  // d_in[3] (bias) cancels in both softmaxes.
  float* out = (float*)d_out;                 // fp32 output (verified round 4)
  unsigned short* outw = (unsigned short*)d_out;

  // ws: ~329 KB
  float* ws    = (float*)d_ws;
  float* m_ws  = ws;                                   // 32768 f (128 KB)
  float* colB  = m_ws + (size_t)BSZ * TT;              // 32768 f (128 KB)
  float* a2_ws = colB + (size_t)BSZ * NSEM;            // 2048 f  (8 KB, unused now)
  float* pmax  = a2_ws + BSZ * DIM;                    // 128 f
  float* gpart = pmax + 128;                           // 128 f
  float* part  = gpart + 128;                          // 16384 f (64 KB)

  prep_kernel <<<512, 256, 0, stream>>>(sem, W, colB, outw);
  flash_kernel<<<1024, 256, 0, stream>>>(aud, W, colB, out, outw);
  merge_kernel<<<2048, 256, 0, stream>>>(out, m_ws);
  bw1_kernel  <<<128, 256, 0, stream>>>(m_ws, pmax);
  bw2_kernel  <<<128, 256, 0, stream>>>(aud, m_ws, pmax, gpart, part);
  epi_kernel  <<<(BSZ * TT * 16) / 256, 256, 0, stream>>>(aud, gpart, part, out);
}

// Round 12
// 200.173 us; speedup vs baseline: 1.8614x; 1.0741x over previous
//
#include <hip/hip_runtime.h>
#include <stdint.h>

#define BSZ 16
#define TT  2048
#define NSEM 2048
#define DIM 128
#define ORS 1024          // shorts per output row (512 floats)
#define PSTR 68           // pbuf row stride in shorts (136B -> bank-stagger, measured 0 conflicts)
#define LOG2E 1.4426950408889634f
#define LN2   0.6931471805599453f

typedef __attribute__((ext_vector_type(8))) short short8;
typedef __attribute__((ext_vector_type(4))) float floatx4;

__device__ __forceinline__ unsigned short f2bf(float f){       // RNE
  unsigned u = __float_as_uint(f);
  return (unsigned short)((u + 0x7fffu + ((u >> 16) & 1u)) >> 16);
}
__device__ __forceinline__ unsigned pkbf(float a, float b){    // 2xf32 -> packed bf16 (RNE, HW)
  unsigned r;
  asm("v_cvt_pk_bf16_f32 %0, %1, %2" : "=v"(r) : "v"(a), "v"(b));
  return r;
}
__device__ __forceinline__ float e2(float x){                  // 2^x, single v_exp
#if __has_builtin(__builtin_amdgcn_exp2f)
  return __builtin_amdgcn_exp2f(x);
#else
  return exp2f(x);
#endif
}
__device__ __forceinline__ void ld8f(const float* p, float* v){
  floatx4 a = *(const floatx4*)p;
  floatx4 b = *(const floatx4*)(p + 4);
  v[0]=a[0]; v[1]=a[1]; v[2]=a[2]; v[3]=a[3];
  v[4]=b[0]; v[5]=b[1]; v[6]=b[2]; v[7]=b[3];
}
// async global->LDS: 64 lanes x 16B; LDS dest is wave-uniform base + lane*16.
__device__ __forceinline__ void gload_lds16(const unsigned short* g, unsigned short* l){
  __builtin_amdgcn_global_load_lds((const __attribute__((address_space(1))) void*)g,
                                   (__attribute__((address_space(3))) void*)l, 16, 0, 0);
}
// PINNED 16B global load: asm volatile cannot be sunk/rematerialized by the
// compiler -> result registers stay live from here to use (defeats windowing).
__device__ __forceinline__ short8 gld16(const unsigned short* p){
  short8 r;
  asm volatile("global_load_dwordx4 %0, %1, off"
               : "=v"(r) : "v"(p) : "memory");
  return r;
}
// monotone int key for float atomicMax (works for negatives)
__device__ __forceinline__ unsigned fkey(float f){
  unsigned u = __float_as_uint(f);
  return u ^ ((unsigned)((int)u >> 31) | 0x80000000u);
}
__device__ __forceinline__ float fdec(unsigned k){
  unsigned u = (k & 0x80000000u) ? (k ^ 0x80000000u) : ~k;
  return __uint_as_float(u);
}

// Staging layout (in out buffer, shorts [512,1024) of rows b*TT + c, 1KB each):
//   KST chunk cK (rows 0..511)   : [quad][l15][8] = K[nblk*16+l15][kc*32+quad*8+j]
//   VST chunk cV (rows 512..1023): [quad][l15][8] = V[ntile*64+kt*32+quad*8+j][dc*16+l15]
// One chunk == one coalesced 1KB wave access (16B/lane).

// ---------------- kernel 1: prep ----------------
// grid 512 (b = bx>>5, n0 = (bx&31)*64), 256 thr. colB pre-scaled by LOG2E (exp2 domain).
__global__ __launch_bounds__(256) void prep_kernel(const float* __restrict__ sem,
                                                   const float* __restrict__ W,
                                                   float* __restrict__ colB,
                                                   unsigned short* __restrict__ outw){
  __shared__ unsigned short tile[DIM * 72];        // [d][n] bf16, stride 72 (144B, 16B-mult)
  const int tid = threadIdx.x;
  const int b  = blockIdx.x >> 5;
  const int n0 = (blockIdx.x & 31) * 64;

  // phase 1: row r (64 rows), col chunk c (32 cols)
  const int r = tid >> 2, cc = tid & 3, c = cc * 32;
  const float* src = sem + ((size_t)(b * NSEM + n0 + r)) * DIM + c;
  float v[32];
  ld8f(src, v); ld8f(src + 8, v + 8); ld8f(src + 16, v + 16); ld8f(src + 24, v + 24);
  alignas(16) unsigned short bf[32];
  float cpart = 0.f;
  #pragma unroll
  for (int j = 0; j < 32; ++j){
    bf[j] = f2bf(v[j]);
    cpart += v[j] * W[DIM + c + j];                // w2 dot partial
  }
  // KST write: chunk (nblk, kc=cc), row l15 = r&15. 4 x 16B at stride 256B.
  {
    const int nblk = (n0 >> 4) + (r >> 4);
    const int l15r = r & 15;
    unsigned short* base = outw + ((size_t)(b * TT + nblk * 4 + cc)) * ORS + 512;
    const uint4* s4 = (const uint4*)bf;
    #pragma unroll
    for (int q = 0; q < 4; ++q)
      *(uint4*)(base + q * 128 + l15r * 8) = s4[q];
  }
  // LDS transpose stage
  #pragma unroll
  for (int j = 0; j < 32; ++j) tile[(c + j) * 72 + r] = bf[j];
  // colB reduce over the 4 col-chunks (lanes differing in bits 0..1)
  cpart += __shfl_xor(cpart, 1);
  cpart += __shfl_xor(cpart, 2);
  if (cc == 0) colB[b * NSEM + n0 + r] = cpart * LOG2E;   // exp2 domain
  __syncthreads();

  // phase 2: VST write. kt = tid>>7 (2), dc = (tid>>4)&7 (8), l15 = tid&15.
  {
    const int kt = tid >> 7, dc = (tid >> 4) & 7, l15 = tid & 15;
    const int d = dc * 16 + l15;
    const int ntile = n0 >> 6;
    unsigned short* base = outw + ((size_t)(b * TT + 512 + ntile * 16 + kt * 8 + dc)) * ORS + 512;
    #pragma unroll
    for (int q = 0; q < 4; ++q){
      uint4 tv = *(const uint4*)&tile[d * 72 + kt * 32 + q * 8];
      *(uint4*)(base + q * 128 + l15 * 8) = tv;
    }
  }
}

// ---------------- kernel 2: flash attention (R7 structure + pinned V regs) ----------------
// grid 512 (b = bx>>5, 64-row t-block), 256 thr = 4 waves; wave wv owns 16 t-rows.
// K: LDS double-buffered via global_load_lds (wrap-prefetch, uniform vmcnt count).
// V: 16 inline-asm global loads at iter top -> PINNED in registers until PV
//    (compiler cannot sink/remat asm volatile); s_waitcnt vmcnt(4) before PV
//    (<=4 outstanding == only the 4 K-DMAs) + sched_barrier fence (rule #18).
// Swapped QK -> row-local softmax in exp2 domain; cvt_pk P pack; defer-max.
// Also folds bw1: per-wave max of (m_true*ln2 + rowA) -> atomicMax(pmax_u[b]).
__global__ __launch_bounds__(256, 2) void flash_kernel(const float* __restrict__ aud,
                                                    const float* __restrict__ W,
                                                    const float* __restrict__ colB,
                                                    float* __restrict__ m_ws,
                                                    float* __restrict__ outf,
                                                    const unsigned short* __restrict__ outw,
                                                    unsigned* __restrict__ pmax_u){
  __shared__ alignas(16) unsigned short kvt[2][16][512];      // 2 bufs x 16 K-chunks x 1KB = 32 KB
  __shared__ alignas(16) unsigned short pbuf[4][16 * PSTR];   // per-wave P staging, 8704 B

  const int tid  = threadIdx.x;
  const int wv   = tid >> 6;
  const int lane = tid & 63;
  const int quad = lane >> 4;
  const int l15  = lane & 15;
  const int b    = blockIdx.x >> 5;
  const int t0w  = (blockIdx.x & 31) * 64 + wv * 16;          // this wave's 16 rows

  // per-lane global staging base (shorts [512,1024) of rows b*TT + c)
  const unsigned short* stage = outw + (size_t)b * TT * ORS + 512 + lane * 8;

  // prologue: stage K tile 0 (chunks j = wv*4..wv*4+3)
  #pragma unroll
  for (int jj = 0; jj < 4; ++jj){
    const int j = wv * 4 + jj;
    gload_lds16(stage + (size_t)j * ORS, &kvt[0][j][0]);
  }

  // q A-frags (aud*w3*log2e -> bf16, exp2 domain) + rowA partial (fp32 dot aud,w1)
  const float* audRow = aud + ((size_t)b * TT + t0w + l15) * DIM;
  short8 qf[4];
  float rowA_part = 0.f;
  #pragma unroll
  for (int kc = 0; kc < 4; ++kc){
    int d0 = kc * 32 + quad * 8;
    float av[8], w3v[8], w1v[8];
    ld8f(audRow + d0, av);
    ld8f(W + 2 * DIM + d0, w3v);
    ld8f(W + d0, w1v);
    alignas(16) unsigned short tmp[8];
    #pragma unroll
    for (int j = 0; j < 8; ++j){
      tmp[j] = f2bf(av[j] * (w3v[j] * LOG2E));
      rowA_part += av[j] * w1v[j];
    }
    qf[kc] = *(const short8*)tmp;
  }
  rowA_part += __shfl_xor(rowA_part, 16);
  rowA_part += __shfl_xor(rowA_part, 32);   // full-d dot for row t0w + l15, replicated

  float m_run = -1e30f, l_run = 0.f;        // per-lane: row t = t0w + l15 (exp2 domain)
  float m_true = -1e30f;                    // exact running max (exp2 domain)
  floatx4 o[8];
  #pragma unroll
  for (int dc = 0; dc < 8; ++dc){
    #pragma unroll
    for (int r = 0; r < 4; ++r) o[dc][r] = 0.f;
  }

  const float* colBb = colB + b * NSEM;
  unsigned short* pb = &pbuf[wv][0];

  __syncthreads();                                  // K tile 0 staged

  for (int it = 0; it < 32; ++it){
    const int n0 = it * 64;

    // colB addends FIRST (compiler-tracked loads; its wait before use counts
    // the later DMAs and leaves them in flight)
    floatx4 cbv[4];
    #pragma unroll
    for (int s = 0; s < 4; ++s) cbv[s] = *(const floatx4*)(colBb + n0 + s*16 + quad*4);

    // ---- V frags: PINNED asm loads (live until PV, not windowable) ----
    const int cV = 512 + it * 16;
    short8 vf[16];
    #pragma unroll
    for (int i = 0; i < 16; ++i) vf[i] = gld16(stage + (size_t)(cV + i) * ORS);

    // ---- prefetch K tile it+1 (wrap: uniform 4 DMAs outstanding every iter) ----
    {
      const int itn = (it + 1) & 31;
      #pragma unroll
      for (int jj = 0; jj < 4; ++jj){
        const int j = wv * 4 + jj;
        gload_lds16(stage + (size_t)(itn * 16 + j) * ORS, &kvt[(it + 1) & 1][j][0]);
      }
    }
    __builtin_amdgcn_sched_barrier(0);      // pin: all VMEM issued before compute

    const unsigned short* kvb = &kvt[it & 1][0][0] + lane * 8;

    // ---- QK swapped: sacc[s] = K_frag x Q -> S[n=quad*4+r][t=l15] (exp2 domain) ----
    floatx4 sacc[4];
    #pragma unroll
    for (int s = 0; s < 4; ++s){ sacc[s][0]=0.f; sacc[s][1]=0.f; sacc[s][2]=0.f; sacc[s][3]=0.f; }
    #pragma unroll
    for (int s = 0; s < 4; ++s){
      #pragma unroll
      for (int kc = 0; kc < 4; ++kc){
        short8 kf = *(const short8*)(kvb + (s*4 + kc) * 512);
        sacc[s] = __builtin_amdgcn_mfma_f32_16x16x32_bf16(kf, qf[kc], sacc[s], 0, 0, 0);
      }
    }

    // ---- online softmax, row-local (t = l15), defer-max THR=8 (log2 units) ----
    float v[4][4];
    #pragma unroll
    for (int s = 0; s < 4; ++s){
      #pragma unroll
      for (int r = 0; r < 4; ++r) v[s][r] = sacc[s][r] + cbv[s][r];
    }
    float mq[4];
    #pragma unroll
    for (int s = 0; s < 4; ++s)
      mq[s] = fmaxf(fmaxf(v[s][0], v[s][1]), fmaxf(v[s][2], v[s][3]));
    float mx = fmaxf(fmaxf(mq[0], mq[1]), fmaxf(mq[2], mq[3]));
    mx = fmaxf(mx, __shfl_xor(mx, 16));
    mx = fmaxf(mx, __shfl_xor(mx, 32));
    m_true = fmaxf(m_true, mx);

    const bool defer = (__all(mx - m_run <= 8.0f) != 0);   // wave-uniform
    float al = 1.0f;
    if (!defer){
      float mnew = fmaxf(m_run, mx);
      al = e2(m_run - mnew);
      m_run = mnew;
    }
    float e[4][4];
    #pragma unroll
    for (int s = 0; s < 4; ++s){
      #pragma unroll
      for (int r = 0; r < 4; ++r) e[s][r] = e2(v[s][r] - m_run);
    }
    float sq[4];
    #pragma unroll
    for (int s = 0; s < 4; ++s)
      sq[s] = (e[s][0] + e[s][1]) + (e[s][2] + e[s][3]);
    float ps = (sq[0] + sq[1]) + (sq[2] + sq[3]);
    ps += __shfl_xor(ps, 16);
    ps += __shfl_xor(ps, 32);
    l_run = l_run * al + ps;

    // P staging (measured 0 conflicts): hw cvt_pk pairs -> 2x ds_write_b32
    #pragma unroll
    for (int s = 0; s < 4; ++s){
      unsigned u0 = pkbf(e[s][0], e[s][1]);
      unsigned u1 = pkbf(e[s][2], e[s][3]);
      unsigned short* pr = pb + l15 * PSTR + s * 16 + quad * 4;
      *(unsigned*)(pr)     = u0;
      *(unsigned*)(pr + 2) = u1;
    }

    // o-rescale only when max actually moved (rare after warm-up)
    if (!defer){
      float aB[4];
      #pragma unroll
      for (int r = 0; r < 4; ++r) aB[r] = __shfl(al, quad*4 + r);
      #pragma unroll
      for (int dc = 0; dc < 8; ++dc){
        #pragma unroll
        for (int r = 0; r < 4; ++r) o[dc][r] *= aB[r];
      }
    }

    // wave-local LDS visibility (in-order DS per wave; just drain writes)
    asm volatile("s_waitcnt lgkmcnt(0)" ::: "memory");
    short8 pf0 = *(const short8*)(pb + l15 * PSTR + quad * 8);
    short8 pf1 = *(const short8*)(pb + l15 * PSTR + 32 + quad * 8);

    // V complete (<=4 outstanding == the 4 K-DMAs only); fence MFMA hoisting
    asm volatile("s_waitcnt vmcnt(4)" ::: "memory");
    __builtin_amdgcn_sched_barrier(0);

    // ---- PV: O += P . sem, V frags pinned in regs ----
    #pragma unroll
    for (int kt = 0; kt < 2; ++kt){
      short8 pf = kt ? pf1 : pf0;
      #pragma unroll
      for (int dc = 0; dc < 8; ++dc)
        o[dc] = __builtin_amdgcn_mfma_f32_16x16x32_bf16(pf, vf[kt*8 + dc], o[dc], 0, 0, 0);
    }

    // tile boundary: K-buffer swap safety + DMA drain
    __syncthreads();
  }

  // ---- epilogue: h = O/l -> out seg1 (fp32); m_true (+rowA) -> ws; bw1 fused ----
  float rl = 1.0f / l_run;
  float rB[4];
  #pragma unroll
  for (int r = 0; r < 4; ++r) rB[r] = __shfl(rl, quad*4 + r);
  float* outB = outf + ((size_t)b * TT + t0w) * 512 + 128;
  #pragma unroll
  for (int dc = 0; dc < 8; ++dc){
    #pragma unroll
    for (int r = 0; r < 4; ++r)
      outB[(size_t)(quad*4 + r) * 512 + dc*16 + l15] = o[dc][r] * rB[r];
  }
  float mval = m_true * LN2 + rowA_part;    // natural domain, per row t0w+l15
  if (quad == 0)
    m_ws[(size_t)b * TT + t0w + l15] = mval;
  // fused bw1: wave max over 16 rows -> atomicMax into pmax_u[b]
  mval = fmaxf(mval, __shfl_xor(mval, 1));
  mval = fmaxf(mval, __shfl_xor(mval, 2));
  mval = fmaxf(mval, __shfl_xor(mval, 4));
  mval = fmaxf(mval, __shfl_xor(mval, 8));
  if (lane == 0) atomicMax(pmax_u + b, fkey(mval));
}

// ---------------- kernel 3: partial exp-sum + partial a2 ----------------
__global__ __launch_bounds__(256) void bw2_kernel(const float* __restrict__ aud,
                                                  const float* __restrict__ m_ws,
                                                  const unsigned* __restrict__ pmax_u,
                                                  float* __restrict__ gpart,
                                                  float* __restrict__ part){
  __shared__ float wbuf[256];
  __shared__ float red[16 * 128];
  __shared__ float gs4[4];
  const int b = blockIdx.x >> 3, ch = blockIdx.x & 7, tid = threadIdx.x;

  float gmax = fdec(pmax_u[b]);

  float w = __expf(m_ws[(size_t)b * TT + ch * 256 + tid] - gmax);
  wbuf[tid] = w;
  float sm = w;
  #pragma unroll
  for (int off = 1; off < 64; off <<= 1) sm += __shfl_xor(sm, off);
  if ((tid & 63) == 0) gs4[tid >> 6] = sm;
  __syncthreads();
  if (tid == 0) gpart[blockIdx.x] = (gs4[0] + gs4[1]) + (gs4[2] + gs4[3]);

  const int dg = tid & 15, q = tid >> 4;
  float acc[8] = {0,0,0,0,0,0,0,0};
  const float* ab = aud + ((size_t)b * TT + ch * 256 + q * 16) * DIM + dg * 8;
  for (int i = 0; i < 16; ++i){
    float av[8];
    ld8f(ab + (size_t)i * DIM, av);
    float wt = wbuf[q * 16 + i];
    #pragma unroll
    for (int j = 0; j < 8; ++j) acc[j] += wt * av[j];
  }
  #pragma unroll
  for (int j = 0; j < 8; ++j) red[q * 128 + dg * 8 + j] = acc[j];
  __syncthreads();
  if (tid < 128){
    float s = 0.f;
    #pragma unroll
    for (int q2 = 0; q2 < 16; ++q2) s += red[q2 * 128 + tid];
    part[(size_t)blockIdx.x * 128 + tid] = s;
  }
}

// ---------------- kernel 4: read seg1 (h) + bw partials, write seg0/2/3 ----------------
// bw3 fused: per block (fixed b) reduce part/gpart -> a2[128] in LDS once.
__global__ __launch_bounds__(256) void epi_kernel(const float* __restrict__ aud,
                                                  const float* __restrict__ gpart,
                                                  const float* __restrict__ part,
                                                  float* __restrict__ out){
  __shared__ float a2s[DIM];
  int id = blockIdx.x * 256 + threadIdx.x;        // BSZ*TT*16
  int c = id & 15;
  int t = (id >> 4) & (TT - 1);
  int b = id >> 15;
  size_t row = (size_t)b * TT + t;

  if (threadIdx.x < 128){
    const int d = threadIdx.x;
    float s = 0.f, g = 0.f;
    #pragma unroll
    for (int ch = 0; ch < 8; ++ch){
      s += part[(size_t)(b * 8 + ch) * 128 + d];
      g += gpart[b * 8 + ch];
    }
    a2s[d] = s / g;
  }
  __syncthreads();

  float av[8], gv[8], hv[8];
  ld8f(aud + row * DIM + c * 8, av);
  ld8f(out + row * 512 + 128 + c * 8, hv);        // h (seg1)
  #pragma unroll
  for (int j = 0; j < 8; ++j) gv[j] = a2s[c * 8 + j];

  floatx4 o0a, o0b, o2a, o2b, o3a, o3b;
  #pragma unroll
  for (int j = 0; j < 4; ++j){
    o0a[j] = av[j];           o0b[j] = av[4+j];
    o2a[j] = av[j]*hv[j];     o2b[j] = av[4+j]*hv[4+j];
    o3a[j] = av[j]*gv[j];     o3b[j] = av[4+j]*gv[4+j];
  }
  float* ob = out + row * 512 + c * 8;
  *(floatx4*)(ob)       = o0a;  *(floatx4*)(ob + 4)   = o0b;   // seg0: aud
  *(floatx4*)(ob + 256) = o2a;  *(floatx4*)(ob + 260) = o2b;   // seg2: aud*h
  *(floatx4*)(ob + 384) = o3a;  *(floatx4*)(ob + 388) = o3b;   // seg3: aud*a2
}

extern "C" void kernel_launch(void* const* d_in, const int* in_sizes, int n_in,
                              void* d_out, int out_size, void* d_ws, size_t ws_size,
                              hipStream_t stream){
  const float* aud = (const float*)d_in[0];   // fp32 inputs (verified round 4)
  const float* sem = (const float*)d_in[1];
  const float* W   = (const float*)d_in[2];
  // d_in[3] (bias) cancels in both softmaxes.
  float* out = (float*)d_out;                 // fp32 output (verified round 4)
  unsigned short* outw = (unsigned short*)d_out;

  // ws: ~329 KB
  float* ws      = (float*)d_ws;
  float* m_ws    = ws;                                 // 32768 f (128 KB)
  float* colB    = m_ws + (size_t)BSZ * TT;            // 32768 f (128 KB)
  float* a2_ws   = colB + (size_t)BSZ * NSEM;          // 2048 f  (8 KB, unused now)
  unsigned* pmax_u = (unsigned*)(a2_ws + BSZ * DIM);   // 16 u32 (as keys)
  float* gpart   = (float*)pmax_u + 128;               // 128 f
  float* part    = gpart + 128;                        // 16384 f (64 KB)

  hipMemsetAsync(pmax_u, 0, BSZ * sizeof(unsigned), stream);   // fkey identity (< fkey(-inf))
  prep_kernel <<<512, 256, 0, stream>>>(sem, W, colB, outw);
  flash_kernel<<<512, 256, 0, stream>>>(aud, W, colB, m_ws, out, outw, pmax_u);
  bw2_kernel  <<<128, 256, 0, stream>>>(aud, m_ws, pmax_u, gpart, part);
  epi_kernel  <<<(BSZ * TT * 16) / 256, 256, 0, stream>>>(aud, gpart, part, out);
}